// Round 12
// baseline (275.099 us; speedup 1.0000x reference)
//
#include <hip/hip_runtime.h>
#include <hip/hip_bf16.h>
#include <string.h>

typedef __hip_bfloat16 bf16;
typedef __bf16 bf16x8 __attribute__((ext_vector_type(8)));
typedef float f32x4 __attribute__((ext_vector_type(4)));

typedef __attribute__((address_space(1))) void* gas_ptr;
typedef __attribute__((address_space(3))) void* las_ptr;

__device__ __forceinline__ void gload_lds16(const void* g, void* l) {
  __builtin_amdgcn_global_load_lds((gas_ptr)(void*)g, (las_ptr)l, 16, 0, 0);
}

// Inputs confirmed fp32 (rounds 2-11 passed with fp32 path).

// ---------------- quaternion block expansion helper (prep role) ----------------
__device__ __forceinline__ void qexpand(const float* r, const float* i_, const float* j_,
                                        const float* k_, bf16* dst, int O4, int I4, int taps,
                                        int gid) {
  int C = 4 * I4;
  int o   = gid / (taps * C);
  int rem = gid % (taps * C);
  int tap = rem / C, c = rem % C;
  int br = o / O4, orr = o % O4, bc = c / I4, ic = c % I4;
  const float* srcs[4] = { r, i_, j_, k_ };
  const int   comp[4][4] = { {0,1,2,3}, {1,0,3,2}, {2,3,0,1}, {3,2,1,0} };
  const float sgn [4][4] = { {1,-1,-1,-1}, {1,1,-1,1}, {1,1,1,-1}, {1,-1,1,1} };
  float v = srcs[comp[br][bc]][(size_t)(orr * I4 + ic) * taps + tap];
  dst[gid] = __float2bfloat16(v * sgn[br][bc]);
}

// ---------------- D1: qkv1f role (blocks 0..511) + prep role (rest) ----------------
#define N_W2 1327104
#define N_W3 16384
#define N_BR 396288
#define N_SQ 512
#define N_SR 8192
#define N_CT 64
#define N_PREP2 (N_W2 + N_W3 + N_BR + N_SQ + N_SR + N_CT)
#define PREP2_BLOCKS ((N_PREP2 + 255) / 256)

__global__ __launch_bounds__(256) void qkv1_prep(
    const float* __restrict__ x,
    const float* __restrict__ qr, const float* __restrict__ qi,
    const float* __restrict__ qj, const float* __restrict__ qk,
    const float* __restrict__ qkv_b,
    const float* __restrict__ dr, const float* __restrict__ di,
    const float* __restrict__ dj, const float* __restrict__ dk,
    const float* __restrict__ pr, const float* __restrict__ pi,
    const float* __restrict__ pj, const float* __restrict__ pk,
    bf16* __restrict__ W2t, bf16* __restrict__ W3t,
    bf16* __restrict__ q1p,
    float* __restrict__ ssq, float* __restrict__ Sraw, int* __restrict__ ctr) {
  const int lid = blockIdx.x;
  const int tid = threadIdx.x;
  if (lid >= 512) {
    int gid = (lid - 512) * 256 + tid;
    if (gid < N_W2) { qexpand(dr, di, dj, dk, W2t, 96, 96, 9, gid); return; }
    gid -= N_W2;
    if (gid < N_W3) { qexpand(pr, pi, pj, pk, W3t, 32, 32, 1, gid); return; }
    gid -= N_W3;
    if (gid < N_BR) {
      int b = gid / (516 * 384);
      int rem = gid % (516 * 384);
      int cell = rem / 384, c = rem % 384;
      int hp, wp;
      if      (cell < 130) { hp = 0;   wp = cell; }
      else if (cell < 260) { hp = 129; wp = cell - 130; }
      else if (cell < 388) { hp = cell - 260 + 1; wp = 0; }
      else                 { hp = cell - 388 + 1; wp = 129; }
      q1p[((size_t)((b * 130 + hp) * 130) + wp) * 384 + c] = __float2bfloat16(0.0f);
      return;
    }
    gid -= N_BR;
    if (gid < N_SQ) { ssq[gid] = 0.0f; return; }
    gid -= N_SQ;
    if (gid < N_SR) { Sraw[gid] = 0.0f; return; }
    gid -= N_SR;
    if (gid < N_CT) { ctr[gid] = 0; return; }
    return;
  }
  // ---- qkv1f role: x NCHW fp32 -> LDS transpose -> 3 o-tiles; W1 tile built inline (vectorized) ----
  __shared__ __align__(16) bf16 Axl[4 * 64 * 32];   // 16 KB
  __shared__ __align__(16) bf16 Bl [4 * 128 * 32];  // 32 KB
  const int h = lid & 127, wh = (lid >> 7) & 1, b = (lid >> 8) & 1;
  const int wid = tid >> 6, lane = tid & 63;
  const int l16 = lane & 15, q = lane >> 4;
  const int wm = (wid & 1) * 32, wn = (wid >> 1) * 64;
  {
    const int c = tid >> 1, seg = tid & 1;
    const float* src = x + ((size_t)(b * 128 + c) << 14) + h * 128 + wh * 64 + seg * 32;
    bf16* dstc = Axl + (c >> 5) * 2048 + (c & 31);
    for (int j = 0; j < 8; ++j) {
      float4 v = *(const float4*)(src + j * 4);
      int w0 = seg * 32 + j * 4;
      dstc[(w0 + 0) * 32] = __float2bfloat16(v.x);
      dstc[(w0 + 1) * 32] = __float2bfloat16(v.y);
      dstc[(w0 + 2) * 32] = __float2bfloat16(v.z);
      dstc[(w0 + 3) * 32] = __float2bfloat16(v.w);
    }
  }
  const float* qsrc[4] = { qr, qi, qj, qk };
  const float sgn[4][4] = { {1,-1,-1,-1}, {1,1,-1,1}, {1,1,1,-1}, {1,-1,1,1} };
  for (int ot = 0; ot < 3; ++ot) {
    __syncthreads();
    // build Bl[bc*4096 + o_l*32 + ic] for this o-tile, 16B chunks (8 ic share sel & sign)
    {
      const int o_l = tid >> 1, hf = tid & 1;
      const int o_g = ot * 128 + o_l;
      const int br = o_g / 96, orr = o_g % 96;
      for (int bc2 = 0; bc2 < 2; ++bc2) {
        int bc = hf * 2 + bc2;
        const float* sp = qsrc[br ^ bc] + orr * 32;
        float sg = sgn[br][bc];
        for (int part = 0; part < 4; ++part) {
          float4 v0 = *(const float4*)(sp + part * 8);
          float4 v1 = *(const float4*)(sp + part * 8 + 4);
          bf16 e[8];
          e[0] = __float2bfloat16(v0.x * sg); e[1] = __float2bfloat16(v0.y * sg);
          e[2] = __float2bfloat16(v0.z * sg); e[3] = __float2bfloat16(v0.w * sg);
          e[4] = __float2bfloat16(v1.x * sg); e[5] = __float2bfloat16(v1.y * sg);
          e[6] = __float2bfloat16(v1.z * sg); e[7] = __float2bfloat16(v1.w * sg);
          *(int4*)&Bl[bc * 4096 + o_l * 32 + part * 8] = *(const int4*)e;
        }
      }
    }
    __syncthreads();
    f32x4 acc[2][4] = {};
    for (int k = 0; k < 4; ++k) {
      bf16x8 af[2], bfr[4];
      for (int mi = 0; mi < 2; ++mi)
        af[mi] = *(const bf16x8*)&Axl[k * 2048 + (wm + mi * 16 + l16) * 32 + q * 8];
      for (int ni = 0; ni < 4; ++ni)
        bfr[ni] = *(const bf16x8*)&Bl[k * 4096 + (wn + ni * 16 + l16) * 32 + q * 8];
      for (int mi = 0; mi < 2; ++mi)
        for (int ni = 0; ni < 4; ++ni)
          acc[mi][ni] = __builtin_amdgcn_mfma_f32_16x16x32_bf16(af[mi], bfr[ni], acc[mi][ni], 0, 0, 0);
    }
    for (int ni = 0; ni < 4; ++ni) {
      int o = ot * 128 + wn + ni * 16 + l16;
      float bv = qkv_b[o];
      for (int mi = 0; mi < 2; ++mi) {
        int w0 = wh * 64 + wm + mi * 16 + q * 4;
        for (int r = 0; r < 4; ++r) {
          int w = w0 + r;
          size_t idx = ((size_t)((b * 130 + h + 1) * 130) + (w + 1)) * 384 + o;
          q1p[idx] = __float2bfloat16(acc[mi][ni][r] + bv);
        }
      }
    }
  }
}

// ---------------- D2: conv3x3 (R9 zero-tail version, unchanged) ----------------
__global__ __launch_bounds__(256, 2) void conv3x3(const bf16* __restrict__ in,
                                                  const bf16* __restrict__ wt,
                                                  const float* __restrict__ bias,
                                                  bf16* __restrict__ out) {
  __shared__ __align__(16) short Al[6 * 132 * 32];
  __shared__ __align__(16) short Bl[9 * 48 * 32];
  const int lid = blockIdx.x;
  const int xcd = lid & 7, slot = lid >> 3;
  const int b = xcd & 1;
  const int h0 = (xcd >> 1) * 32 + (slot & 7) * 4;
  const int ob = (slot >> 3) * 48;
  const int tid = threadIdx.x, wid = tid >> 6, lane = tid & 63;
  const int l16 = lane & 15, q = lane >> 4;
  f32x4 acc[8][3] = {};
  const bf16* abase = in + (size_t)b * 130 * 130 * 384;
  const bf16* bbase = wt + (size_t)ob * 3456;
  for (int c0 = 0; c0 < 384; c0 += 32) {
    __syncthreads();
    for (int i = 0; i < 12; ++i) {
      int g = wid * 792 + i * 64;
      int ci = g + lane;
      int row = ci / 528, rem = ci % 528;
      int w = rem >> 2, part = rem & 3;
      gload_lds16(abase + ((size_t)(h0 + row) * 130 + w) * 384 + c0 + part * 8, &Al[g * 8]);
    }
    if (lane < 24) {
      int g = wid * 792 + 768;
      int ci = g + lane;
      int row = ci / 528, rem = ci % 528;
      int w = rem >> 2, part = rem & 3;
      gload_lds16(abase + ((size_t)(h0 + row) * 130 + w) * 384 + c0 + part * 8, &Al[g * 8]);
    }
    for (int i = 0; i < 6; ++i) {
      int g = wid * 432 + i * 64;
      int ci = g + lane;
      int tap = ci / 192, rem = ci % 192;
      int o = rem >> 2, part = rem & 3;
      gload_lds16(bbase + (size_t)o * 3456 + tap * 384 + c0 + part * 8, &Bl[g * 8]);
    }
    if (lane < 48) {
      int g = wid * 432 + 384;
      int ci = g + lane;
      int tap = ci / 192, rem = ci % 192;
      int o = rem >> 2, part = rem & 3;
      gload_lds16(bbase + (size_t)o * 3456 + tap * 384 + c0 + part * 8, &Bl[g * 8]);
    }
    __syncthreads();
    for (int dh = 0; dh < 3; ++dh)
      for (int dw = 0; dw < 3; ++dw) {
        bf16x8 af[8], bfr[3];
        for (int mi = 0; mi < 8; ++mi)
          af[mi] = *(const bf16x8*)&Al[((wid + dh) * 132 + mi * 16 + l16 + dw) * 32 + q * 8];
        for (int ni = 0; ni < 3; ++ni)
          bfr[ni] = *(const bf16x8*)&Bl[((dh * 3 + dw) * 48 + ni * 16 + l16) * 32 + q * 8];
        for (int mi = 0; mi < 8; ++mi)
          for (int ni = 0; ni < 3; ++ni)
            acc[mi][ni] = __builtin_amdgcn_mfma_f32_16x16x32_bf16(af[mi], bfr[ni], acc[mi][ni], 0, 0, 0);
      }
  }
  const int h = h0 + wid;
  for (int ni = 0; ni < 3; ++ni) {
    int o = ob + ni * 16 + l16;
    float bv = bias[o];
    for (int mi = 0; mi < 8; ++mi) {
      int w0 = mi * 16 + q * 4;
      for (int r = 0; r < 4; ++r) {
        int w = w0 + r;
        out[((size_t)(b * 16384 + h * 128 + w)) * 384 + o] = __float2bfloat16(acc[mi][ni][r] + bv);
      }
    }
  }
}

// ---------------- D3: attn, phase-merged (same 256 blocks do qk, barrier, out) ----------------
__global__ __launch_bounds__(256) void attn_phased(const bf16* __restrict__ q2,
                                                   float* __restrict__ Sraw,
                                                   float* __restrict__ ssq,
                                                   const float* __restrict__ temp,
                                                   const bf16* __restrict__ w3,
                                                   const float* __restrict__ po_b,
                                                   int* __restrict__ ctr,
                                                   float* __restrict__ out) {
  __shared__ bf16 qt[64][32];
  __shared__ bf16 kt[64][32];
  __shared__ float Sl[1024];
  __shared__ float nql[32], nkl[32];
  __shared__ __align__(16) bf16 Ml[4 * 128 * 32];
  __shared__ float Pl[4][32][32];
  __shared__ __align__(16) short Vl[128 * 32];
  __shared__ float rqa[128], rka[128];
  const int lid = blockIdx.x;
  const int t = threadIdx.x;
  const int wid = t >> 6, lane = t & 63;
  const int l16 = lane & 15, q = lane >> 4;

  // ------- phase 1: qk (R9 attn_qk body) -------
  {
    const int sc = lid & 31, h = (lid >> 5) & 3, b = lid >> 7;
    for (int i = t; i < 1024; i += 256) Sl[i] = 0.0f;
    if (t < 32) nql[t] = 0.0f;
    else if (t < 64) nkl[t - 32] = 0.0f;
    const int slq = t >> 2, seg = t & 3;
    const int slot = t & 63, sg = t >> 6;
    const int cg = (slot & 7) * 4, dg = (slot >> 3) * 4;
    float acc[4][4] = {};
    float sq[4] = {}, sk[4] = {};
    for (int it = 0; it < 8; ++it) {
      int sbase = sc * 512 + it * 64;
      __syncthreads();
      {
        size_t rq = ((size_t)(b * 16384 + sbase + slq)) * 384 + h * 32 + seg * 8;
        *(bf16x8*)&qt[slq][seg * 8] = *(const bf16x8*)&q2[rq];
        *(bf16x8*)&kt[slq][seg * 8] = *(const bf16x8*)&q2[rq + 128];
      }
      __syncthreads();
      for (int sl = sg * 16; sl < sg * 16 + 16; ++sl) {
        float qv[4], kv[4];
        for (int a = 0; a < 4; ++a) qv[a] = __bfloat162float(qt[sl][cg + a]);
        for (int d = 0; d < 4; ++d) kv[d] = __bfloat162float(kt[sl][dg + d]);
        if (dg == 0) for (int a = 0; a < 4; ++a) sq[a] += qv[a] * qv[a];
        if (cg == 0) for (int d = 0; d < 4; ++d) sk[d] += kv[d] * kv[d];
        for (int a = 0; a < 4; ++a)
          for (int d = 0; d < 4; ++d) acc[a][d] += qv[a] * kv[d];
      }
    }
    for (int a = 0; a < 4; ++a)
      for (int d = 0; d < 4; ++d)
        atomicAdd(&Sl[(cg + a) * 32 + dg + d], acc[a][d]);
    if (dg == 0) for (int a = 0; a < 4; ++a) atomicAdd(&nql[cg + a], sq[a]);
    if (cg == 0) for (int d = 0; d < 4; ++d) atomicAdd(&nkl[dg + d], sk[d]);
    __syncthreads();
    float* Sg = Sraw + (size_t)((b * 4 + h) * 1024);
    for (int i = t * 4; i < t * 4 + 4; ++i) atomicAdd(&Sg[i], Sl[i]);
    if (t < 32) atomicAdd(&ssq[b * 256 + h * 32 + t], nql[t]);
    else if (t < 64) atomicAdd(&ssq[b * 256 + 128 + h * 32 + (t - 32)], nkl[t - 32]);
    __threadfence();
    __syncthreads();
    if (t == 0) __hip_atomic_fetch_add(ctr, 1, __ATOMIC_RELEASE, __HIP_MEMORY_SCOPE_AGENT);
  }
  // ------- barrier: wait for all 256 blocks (skew only; throttled poll) -------
  if (t == 0) {
    long spins = 0;
    while (__hip_atomic_load(ctr, __ATOMIC_ACQUIRE, __HIP_MEMORY_SCOPE_AGENT) < 256) {
      __builtin_amdgcn_s_sleep(2);
      if (++spins > 100000000L) break;   // safety valve
    }
  }
  __syncthreads();
  __threadfence();
  // ------- phase 2: out (R9 attn_out body), tile = lid -------
  const int b = lid >> 7, s0 = (lid & 127) * 128;
  {
    float v = __hip_atomic_load(&ssq[b * 256 + t], __ATOMIC_RELAXED, __HIP_MEMORY_SCOPE_AGENT);
    float rv = 1.0f / fmaxf(sqrtf(fmaxf(v, 0.0f)), 1e-12f);
    if (t < 128) rqa[t] = rv; else rka[t - 128] = rv;
  }
  __syncthreads();
  if (t < 128) {
    int hh = t >> 5, c = t & 31;
    const float* Sr = Sraw + ((size_t)((b * 4 + hh) * 32 + c)) * 32;
    float tv = temp[hh];
    float rq = rqa[t];
    float row[32];
    float m = -1e30f;
    for (int d = 0; d < 32; ++d) {
      float sv = __hip_atomic_load(&Sr[d], __ATOMIC_RELAXED, __HIP_MEMORY_SCOPE_AGENT);
      row[d] = sv * tv * rq * rka[hh * 32 + d];
      m = fmaxf(m, row[d]);
    }
    float sum = 0.0f;
    for (int d = 0; d < 32; ++d) { row[d] = expf(row[d] - m); sum += row[d]; }
    float inv = 1.0f / sum;
    for (int d = 0; d < 32; ++d) Pl[hh][c][d] = row[d] * inv;
  }
  __syncthreads();
  {
    const int o = t >> 1, half = t & 1;
    for (int hh2 = 0; hh2 < 2; ++hh2) {
      int hv = half * 2 + hh2;
      float w3r[32];
      const bf16* wrow = w3 + o * 128 + hv * 32;
      for (int c = 0; c < 32; ++c) w3r[c] = __bfloat162float(wrow[c]);
      for (int d = 0; d < 32; ++d) {
        float s = 0.0f;
        for (int c = 0; c < 32; ++c) s += w3r[c] * Pl[hv][c][d];
        Ml[hv * 4096 + o * 32 + d] = __float2bfloat16(s);
      }
    }
  }
  f32x4 acc[4][4] = {};
  const int wmo = (wid & 1) * 64, wns = (wid >> 1) * 64;
  for (int kc = 0; kc < 4; ++kc) {
    __syncthreads();
    for (int i = 0; i < 2; ++i) {
      int ci = i * 256 + t;
      int s = ci >> 2, part = ci & 3;
      gload_lds16(q2 + ((size_t)(b * 16384 + s0 + s)) * 384 + 256 + kc * 32 + part * 8,
                  &Vl[(size_t)(i * 256 + wid * 64) * 8]);
    }
    __syncthreads();
    bf16x8 af[4], bfr[4];
    for (int mi = 0; mi < 4; ++mi)
      af[mi] = *(const bf16x8*)&Ml[kc * 4096 + (wmo + mi * 16 + l16) * 32 + q * 8];
    for (int ni = 0; ni < 4; ++ni)
      bfr[ni] = *(const bf16x8*)&Vl[(wns + ni * 16 + l16) * 32 + q * 8];
    for (int mi = 0; mi < 4; ++mi)
      for (int ni = 0; ni < 4; ++ni)
        acc[mi][ni] = __builtin_amdgcn_mfma_f32_16x16x32_bf16(af[mi], bfr[ni], acc[mi][ni], 0, 0, 0);
  }
  for (int ni = 0; ni < 4; ++ni) {
    int s = s0 + wns + ni * 16 + l16;
    for (int mi = 0; mi < 4; ++mi) {
      int o0 = wmo + mi * 16 + q * 4;
      for (int r = 0; r < 4; ++r) {
        int o = o0 + r;
        out[(size_t)b * 2097152 + (size_t)o * 16384 + s] = acc[mi][ni][r] + po_b[o];
      }
    }
  }
}

extern "C" void kernel_launch(void* const* d_in, const int* in_sizes, int n_in,
                              void* d_out, int out_size, void* d_ws, size_t ws_size,
                              hipStream_t stream) {
  const float* x     = (const float*)d_in[0];
  const float* qkv_r = (const float*)d_in[1];
  const float* qkv_i = (const float*)d_in[2];
  const float* qkv_j = (const float*)d_in[3];
  const float* qkv_k = (const float*)d_in[4];
  const float* qkv_b = (const float*)d_in[5];
  const float* dw_r  = (const float*)d_in[6];
  const float* dw_i  = (const float*)d_in[7];
  const float* dw_j  = (const float*)d_in[8];
  const float* dw_k  = (const float*)d_in[9];
  const float* dw_b  = (const float*)d_in[10];
  const float* po_r  = (const float*)d_in[11];
  const float* po_i  = (const float*)d_in[12];
  const float* po_j  = (const float*)d_in[13];
  const float* po_k  = (const float*)d_in[14];
  const float* po_b  = (const float*)d_in[15];
  const float* temp  = (const float*)d_in[16];

  char* ws = (char*)d_ws;
  size_t off = 0;
  auto alloc = [&](size_t bytes) { char* p = ws + off; off += (bytes + 255) & ~(size_t)255; return p; };
  bf16* q1p  = (bf16*)alloc((size_t)2 * 130 * 130 * 384 * 2);
  bf16* q2   = (bf16*)alloc((size_t)2 * 16384 * 384 * 2);
  bf16* W2t  = (bf16*)alloc((size_t)384 * 3456 * 2);
  bf16* W3t  = (bf16*)alloc((size_t)128 * 128 * 2);
  float* ssq  = (float*)alloc((size_t)2 * 256 * 4);
  float* Sraw = (float*)alloc((size_t)2 * 4 * 32 * 32 * 4);
  int*   ctr  = (int*)alloc((size_t)N_CT * 4);

  qkv1_prep<<<512 + PREP2_BLOCKS, 256, 0, stream>>>(
      x, qkv_r, qkv_i, qkv_j, qkv_k, qkv_b,
      dw_r, dw_i, dw_j, dw_k,
      po_r, po_i, po_j, po_k,
      W2t, W3t, q1p, ssq, Sraw, ctr);
  conv3x3<<<512, 256, 0, stream>>>(q1p, W2t, dw_b, q2);
  attn_phased<<<256, 256, 0, stream>>>(q2, Sraw, ssq, temp, W3t, po_b, ctr, (float*)d_out);
}